// Round 6
// baseline (1187.521 us; speedup 1.0000x reference)
//
#include <hip/hip_runtime.h>

#define NN 4096
#define NE 65536
#define C 256
#define NL 3
#define NH 8
#define DH 32
#define EPS 1e-5f
#define SPLIT 4          // key-dim split for attention occupancy
#define KT_PER (NN/64/SPLIT)

typedef __bf16 bf16x8 __attribute__((ext_vector_type(8)));
typedef __bf16 bf16x4v __attribute__((ext_vector_type(4)));
typedef float f32x4 __attribute__((ext_vector_type(4)));
typedef short bf16x4s __attribute__((ext_vector_type(4)));   // 4 bf16 as i16x4

// scale * log2(e), folded into Q at projection time so softmax uses exp2
#define QSCALE (0.17677669529663687f * 1.4426950408889634f)

#define CCL (NL*C*C)     // 196608: elems of one [L,C,C] weight group

// ---------------- weight prep: fp32 -> bf16, all 8 groups ----------------
__global__ __launch_bounds__(256) void prep_w(const float* __restrict__ s0,
        const float* __restrict__ s1, const float* __restrict__ s2,
        const float* __restrict__ s3, const float* __restrict__ s4,
        const float* __restrict__ s5, const float* __restrict__ s6,
        const float* __restrict__ s7, __bf16* __restrict__ dst) {
    int g = blockIdx.y;
    int i = (blockIdx.x*256 + threadIdx.x)*4;
    const float* src; size_t off; int n;
    switch (g) {
        case 0: src=s0; off=0;        n=CCL;   break;
        case 1: src=s1; off=CCL;      n=CCL;   break;
        case 2: src=s2; off=2*CCL;    n=CCL;   break;
        case 3: src=s3; off=3*CCL;    n=CCL;   break;
        case 4: src=s4; off=4*CCL;    n=CCL;   break;
        case 5: src=s5; off=5*CCL;    n=CCL;   break;
        case 6: src=s6; off=6*CCL;    n=2*CCL; break;
        default: src=s7; off=8*CCL;   n=2*CCL; break;
    }
    if (i < n) {
        float4 t = *(const float4*)(src + i);
        bf16x4v o = {(__bf16)t.x, (__bf16)t.y, (__bf16)t.z, (__bf16)t.w};
        *(bf16x4v*)(dst + off + i) = o;
    }
}

// ---------------- lin1: h[n,c] = x[n]*w[c] + b[c], bf16 out ----------------
__global__ __launch_bounds__(256) void lin1_kernel(const float* __restrict__ x,
        const float* __restrict__ w, const float* __restrict__ b,
        __bf16* __restrict__ out) {
    int n = blockIdx.x, c = threadIdx.x;
    out[(size_t)n*C + c] = (__bf16)(x[n]*w[c] + b[c]);
}

// ---------------- scatter: agg[dst] += h[src], 4 edges/block ----------------
__global__ __launch_bounds__(256) void scatter_kernel(const __bf16* __restrict__ h,
        const int* __restrict__ ei, float* __restrict__ agg) {
    int tid = threadIdx.x;
    int e = blockIdx.x*4 + (tid >> 6);
    int cq = (tid & 63) * 4;
    int src = ei[e];
    int dst = ei[NE + e];
    bf16x4v v = *(const bf16x4v*)&h[(size_t)src*C + cq];
    #pragma unroll
    for (int j = 0; j < 4; j++)
        atomicAdd(&agg[(size_t)dst*C + cq + j], (float)v[j]);
}

// ---------------- all-bf16 MFMA GEMM ----------------
// out = relu?((A [+A2f|+A2b]) @ W^T + bias) + add1 + add2; bf16 in/out, fp32
// accum. Optional BN partial stats. Tile 64x64, BK=64, 256 thr = 4 waves.
#define GS 72   // LDS row stride in bf16 (144B: rows offset 4 banks -> 2-way, free)
__global__ __launch_bounds__(256) void gemm_bf16(const __bf16* __restrict__ A,
        const float* __restrict__ A2f, const __bf16* __restrict__ A2b,
        const __bf16* __restrict__ W, const float* __restrict__ bias,
        const __bf16* __restrict__ add1, const __bf16* __restrict__ add2,
        __bf16* __restrict__ out, float* __restrict__ stats,
        int K, int Nout, int relu) {
    __shared__ __bf16 As[64*GS];
    __shared__ __bf16 Ws[64*GS];
    int tid = threadIdx.x;
    int wave = tid >> 6, lane = tid & 63;
    int ln = lane & 15, quad = lane >> 4;
    int bm = blockIdx.y * 64, bn = blockIdx.x * 64;
    int row = tid >> 2, kseg = (tid & 3) * 16;
    f32x4 acc[4] = {};
    for (int k0 = 0; k0 < K; k0 += 64) {
        __syncthreads();
        {
            const __bf16* ap = &A[(size_t)(bm+row)*K + k0 + kseg];
            bf16x8 a0 = *(const bf16x8*)ap;
            bf16x8 a1 = *(const bf16x8*)(ap + 8);
            if (A2f) {
                const float* p = &A2f[(size_t)(bm+row)*K + k0 + kseg];
                #pragma unroll
                for (int i = 0; i < 2; i++) {
                    float4 t0 = *(const float4*)(p + i*8);
                    float4 t1 = *(const float4*)(p + i*8 + 4);
                    bf16x8& a = i ? a1 : a0;
                    a[0] = (__bf16)((float)a[0] + t0.x); a[1] = (__bf16)((float)a[1] + t0.y);
                    a[2] = (__bf16)((float)a[2] + t0.z); a[3] = (__bf16)((float)a[3] + t0.w);
                    a[4] = (__bf16)((float)a[4] + t1.x); a[5] = (__bf16)((float)a[5] + t1.y);
                    a[6] = (__bf16)((float)a[6] + t1.z); a[7] = (__bf16)((float)a[7] + t1.w);
                }
            } else if (A2b) {
                const __bf16* p = &A2b[(size_t)(bm+row)*K + k0 + kseg];
                bf16x8 b0 = *(const bf16x8*)p;
                bf16x8 b1 = *(const bf16x8*)(p + 8);
                #pragma unroll
                for (int j = 0; j < 8; j++) {
                    a0[j] = (__bf16)((float)a0[j] + (float)b0[j]);
                    a1[j] = (__bf16)((float)a1[j] + (float)b1[j]);
                }
            }
            *(bf16x8*)&As[row*GS + kseg]     = a0;
            *(bf16x8*)&As[row*GS + kseg + 8] = a1;
            const __bf16* wp = &W[(size_t)(bn+row)*K + k0 + kseg];
            *(bf16x8*)&Ws[row*GS + kseg]     = *(const bf16x8*)wp;
            *(bf16x8*)&Ws[row*GS + kseg + 8] = *(const bf16x8*)(wp + 8);
        }
        __syncthreads();
        #pragma unroll
        for (int kt2 = 0; kt2 < 2; kt2++) {
            bf16x8 bfr = *(const bf16x8*)&Ws[(wave*16+ln)*GS + kt2*32 + quad*8];
            #pragma unroll
            for (int i = 0; i < 4; i++) {
                bf16x8 afr = *(const bf16x8*)&As[(i*16+ln)*GS + kt2*32 + quad*8];
                acc[i] = __builtin_amdgcn_mfma_f32_16x16x32_bf16(afr, bfr, acc[i], 0, 0, 0);
            }
        }
    }
    int col = bn + wave*16 + ln;
    float bsv = bias[col];
    float ssum = 0.f, ssq = 0.f;
    #pragma unroll
    for (int i = 0; i < 4; i++) {
        #pragma unroll
        for (int r = 0; r < 4; r++) {
            int rw = bm + i*16 + quad*4 + r;
            float vv = acc[i][r] + bsv;
            if (relu) vv = fmaxf(vv, 0.f);
            size_t idx = (size_t)rw*Nout + col;
            if (add1) vv += (float)add1[idx];
            if (add2) vv += (float)add2[idx];
            out[idx] = (__bf16)vv;
            ssum += vv; ssq += vv*vv;
        }
    }
    if (stats) {
        ssum += __shfl_xor(ssum, 16); ssum += __shfl_xor(ssum, 32);
        ssq  += __shfl_xor(ssq, 16);  ssq  += __shfl_xor(ssq, 32);
        if (quad == 0) {
            atomicAdd(&stats[col], ssum);
            atomicAdd(&stats[Nout + col], ssq);
        }
    }
}

// ---------------- fused QKV projection, all-bf16 ----------------
__global__ __launch_bounds__(256) void qkv_gemm(const __bf16* __restrict__ A,
        const __bf16* __restrict__ wq, const __bf16* __restrict__ wk,
        const __bf16* __restrict__ wv, const float* __restrict__ bq,
        const float* __restrict__ bk, const float* __restrict__ bv,
        __bf16* __restrict__ qo, __bf16* __restrict__ ko,
        __bf16* __restrict__ vo) {
    int z = blockIdx.z;
    const __bf16* W   = z == 0 ? wq : (z == 1 ? wk : wv);
    const float* bias = z == 0 ? bq : (z == 1 ? bk : bv);
    __bf16* out       = z == 0 ? qo : (z == 1 ? ko : vo);
    float oscale      = z == 0 ? QSCALE : 1.0f;
    __shared__ __bf16 As[64*GS];
    __shared__ __bf16 Ws[64*GS];
    int tid = threadIdx.x;
    int wave = tid >> 6, lane = tid & 63;
    int ln = lane & 15, quad = lane >> 4;
    int bm = blockIdx.y * 64, bn = blockIdx.x * 64;
    int row = tid >> 2, kseg = (tid & 3) * 16;
    f32x4 acc[4] = {};
    for (int k0 = 0; k0 < C; k0 += 64) {
        __syncthreads();
        {
            const __bf16* ap = &A[(size_t)(bm+row)*C + k0 + kseg];
            *(bf16x8*)&As[row*GS + kseg]     = *(const bf16x8*)ap;
            *(bf16x8*)&As[row*GS + kseg + 8] = *(const bf16x8*)(ap + 8);
            const __bf16* wp = &W[(size_t)(bn+row)*C + k0 + kseg];
            *(bf16x8*)&Ws[row*GS + kseg]     = *(const bf16x8*)wp;
            *(bf16x8*)&Ws[row*GS + kseg + 8] = *(const bf16x8*)(wp + 8);
        }
        __syncthreads();
        #pragma unroll
        for (int kt2 = 0; kt2 < 2; kt2++) {
            bf16x8 bfr = *(const bf16x8*)&Ws[(wave*16+ln)*GS + kt2*32 + quad*8];
            #pragma unroll
            for (int i = 0; i < 4; i++) {
                bf16x8 afr = *(const bf16x8*)&As[(i*16+ln)*GS + kt2*32 + quad*8];
                acc[i] = __builtin_amdgcn_mfma_f32_16x16x32_bf16(afr, bfr, acc[i], 0, 0, 0);
            }
        }
    }
    int col = bn + wave*16 + ln;
    float bsv = bias[col];
    #pragma unroll
    for (int i = 0; i < 4; i++)
        #pragma unroll
        for (int r = 0; r < 4; r++) {
            int rw = bm + i*16 + quad*4 + r;
            out[(size_t)rw*C + col] = (__bf16)((acc[i][r] + bsv) * oscale);
        }
}

// ---------------- BatchNorm apply: bf16 in, bf16 or fp32 out ----------------
__global__ __launch_bounds__(256) void bn_apply_kernel(const __bf16* __restrict__ z,
        const float* __restrict__ stats, const float* __restrict__ g,
        const float* __restrict__ b, __bf16* __restrict__ outb,
        float* __restrict__ outf) {
    int idx4 = (blockIdx.x*256 + threadIdx.x) * 4;
    int c = idx4 & (C-1);
    bf16x4v zv = *(const bf16x4v*)&z[idx4];
    float4 st = *(const float4*)&stats[c];
    float4 sq = *(const float4*)&stats[C + c];
    float4 gv = *(const float4*)&g[c];
    float4 bv = *(const float4*)&b[c];
    float o[4];
    float mean0 = st.x*(1.f/NN), mean1 = st.y*(1.f/NN), mean2 = st.z*(1.f/NN), mean3 = st.w*(1.f/NN);
    o[0] = ((float)zv[0] - mean0) * rsqrtf(sq.x*(1.f/NN) - mean0*mean0 + EPS) * gv.x + bv.x;
    o[1] = ((float)zv[1] - mean1) * rsqrtf(sq.y*(1.f/NN) - mean1*mean1 + EPS) * gv.y + bv.y;
    o[2] = ((float)zv[2] - mean2) * rsqrtf(sq.z*(1.f/NN) - mean2*mean2 + EPS) * gv.z + bv.z;
    o[3] = ((float)zv[3] - mean3) * rsqrtf(sq.w*(1.f/NN) - mean3*mean3 + EPS) * gv.w + bv.w;
    if (outb) {
        bf16x4v ov = {(__bf16)o[0], (__bf16)o[1], (__bf16)o[2], (__bf16)o[3]};
        *(bf16x4v*)&outb[idx4] = ov;
    } else {
        float4 ov = {o[0], o[1], o[2], o[3]};
        *(float4*)&outf[idx4] = ov;
    }
}

// ---------------- bf16 MFMA flash attention, S^T formulation ----------------
__global__ __launch_bounds__(256) void attn_kernel(const __bf16* __restrict__ q,
        const __bf16* __restrict__ k, const __bf16* __restrict__ v,
        __bf16* __restrict__ opart, float2* __restrict__ ml) {
    __shared__ __bf16 Ks[64*36];            // [key][dh], row-major, pad 36
    int tid = threadIdx.x;
    int wave = tid >> 6, lane = tid & 63;
    int ln = lane & 15, quad = lane >> 4;
    int head = blockIdx.y;
    int hb = head * DH;
    int qb = blockIdx.x * 128;
    int z = blockIdx.z;

    bf16x8 qf[2];
    #pragma unroll
    for (int g = 0; g < 2; g++)
        qf[g] = *(const bf16x8*)&q[(size_t)(qb + wave*32 + g*16 + ln)*C + hb + quad*8];

    f32x4 oacc[2][2] = {};
    float m_[2], l_[2];
    #pragma unroll
    for (int g = 0; g < 2; g++) { m_[g] = -1e30f; l_[g] = 0.f; }

    int srow = tid >> 2, sseg = (tid & 3) * 8;
    for (int kt = z*KT_PER; kt < (z+1)*KT_PER; kt++) {
        int kb = kt * 64;
        union { __bf16 b[4]; bf16x4s s; } vf[4][2];
        {
            const __bf16* vb = v + ((size_t)kb + quad*4)*C + hb + ln;
            #pragma unroll
            for (int sub = 0; sub < 4; sub++)
                #pragma unroll
                for (int h = 0; h < 2; h++)
                    #pragma unroll
                    for (int j = 0; j < 4; j++)
                        vf[sub][h].b[j] = vb[(size_t)(sub*16 + j)*C + h*16];
        }
        __syncthreads();
        *(bf16x8*)&Ks[srow*36 + sseg] = *(const bf16x8*)&k[(size_t)(kb+srow)*C + hb + sseg];
        __syncthreads();

        f32x4 st[2][4];
        #pragma unroll
        for (int sub = 0; sub < 4; sub++) {
            bf16x8 af = *(const bf16x8*)&Ks[(sub*16+ln)*36 + quad*8];
            #pragma unroll
            for (int g = 0; g < 2; g++) {
                f32x4 zz = {0.f,0.f,0.f,0.f};
                st[g][sub] = __builtin_amdgcn_mfma_f32_16x16x32_bf16(af, qf[g], zz, 0, 0, 0);
            }
        }
        #pragma unroll
        for (int g = 0; g < 2; g++) {
            float tm = st[g][0][0];
            #pragma unroll
            for (int sub = 0; sub < 4; sub++)
                #pragma unroll
                for (int r = 0; r < 4; r++)
                    tm = fmaxf(tm, st[g][sub][r]);
            tm = fmaxf(tm, __shfl_xor(tm, 16));
            tm = fmaxf(tm, __shfl_xor(tm, 32));
            float nm = fmaxf(m_[g], tm);
            float al = __builtin_amdgcn_exp2f(m_[g] - nm);
            m_[g] = nm;
            float ps = 0.f;
            union { __bf16 b[4]; bf16x4s s; } pf[4];
            #pragma unroll
            for (int sub = 0; sub < 4; sub++)
                #pragma unroll
                for (int r = 0; r < 4; r++) {
                    float p = __builtin_amdgcn_exp2f(st[g][sub][r] - nm);
                    pf[sub].b[r] = (__bf16)p;
                    ps += p;
                }
            ps += __shfl_xor(ps, 16);
            ps += __shfl_xor(ps, 32);
            l_[g] = l_[g]*al + ps;
            #pragma unroll
            for (int r = 0; r < 4; r++) {
                float ar = __shfl(al, (lane & 48) | (quad*4 + r));
                oacc[g][0][r] *= ar;
                oacc[g][1][r] *= ar;
            }
            #pragma unroll
            for (int sub = 0; sub < 4; sub++) {
                oacc[g][0] = __builtin_amdgcn_mfma_f32_16x16x16bf16_1k(
                        pf[sub].s, vf[sub][0].s, oacc[g][0], 0, 0, 0);
                oacc[g][1] = __builtin_amdgcn_mfma_f32_16x16x16bf16_1k(
                        pf[sub].s, vf[sub][1].s, oacc[g][1], 0, 0, 0);
            }
        }
    }
    #pragma unroll
    for (int g = 0; g < 2; g++) {
        #pragma unroll
        for (int r = 0; r < 4; r++) {
            float lr = __shfl(l_[g], (lane & 48) | (quad*4 + r));
            float inv = 1.0f / lr;
            int row = qb + wave*32 + g*16 + quad*4 + r;
            size_t base = ((size_t)z*NN + row)*C + hb;
            opart[base + ln]      = (__bf16)(oacc[g][0][r] * inv);
            opart[base + 16 + ln] = (__bf16)(oacc[g][1][r] * inv);
        }
        if (quad == 0) {
            int qrow = qb + wave*32 + g*16 + ln;
            ml[((size_t)z*NH + head)*NN + qrow] = make_float2(m_[g], l_[g]);
        }
    }
}

// ---------------- combine split-K attention partials, bf16 out ----------------
__global__ __launch_bounds__(256) void attn_combine(const __bf16* __restrict__ opart,
        const float2* __restrict__ ml, __bf16* __restrict__ o) {
    int row = blockIdx.x, c = threadIdx.x;
    int head = c >> 5;
    float2 t[SPLIT];
    float M = -1e30f;
    #pragma unroll
    for (int z = 0; z < SPLIT; z++) {
        t[z] = ml[((size_t)z*NH + head)*NN + row];
        M = fmaxf(M, t[z].x);
    }
    float acc = 0.f, wsum = 0.f;
    #pragma unroll
    for (int z = 0; z < SPLIT; z++) {
        float w = t[z].y * __builtin_amdgcn_exp2f(t[z].x - M);
        acc += w * (float)opart[((size_t)z*NN + row)*C + c];
        wsum += w;
    }
    o[(size_t)row*C + c] = (__bf16)(acc / wsum);
}

extern "C" void kernel_launch(void* const* d_in, const int* in_sizes, int n_in,
                              void* d_out, int out_size, void* d_ws, size_t ws_size,
                              hipStream_t stream) {
    const float* x      = (const float*)d_in[0];
    const int*   ei     = (const int*)d_in[1];
    const float* lin1_w = (const float*)d_in[2];
    const float* lin1_b = (const float*)d_in[3];
    const float* gin_w1 = (const float*)d_in[4];
    const float* gin_b1 = (const float*)d_in[5];
    const float* gin_w2 = (const float*)d_in[6];
    const float* gin_b2 = (const float*)d_in[7];
    const float* wq = (const float*)d_in[8];
    const float* wk = (const float*)d_in[9];
    const float* wv = (const float*)d_in[10];
    const float* wo = (const float*)d_in[11];
    const float* bq = (const float*)d_in[12];
    const float* bk = (const float*)d_in[13];
    const float* bv = (const float*)d_in[14];
    const float* bo = (const float*)d_in[15];
    const float* bn1_g = (const float*)d_in[16];
    const float* bn1_b = (const float*)d_in[17];
    const float* bn2_g = (const float*)d_in[18];
    const float* bn2_b = (const float*)d_in[19];
    const float* bn3_g = (const float*)d_in[20];
    const float* bn3_b = (const float*)d_in[21];
    const float* mw1 = (const float*)d_in[22];
    const float* mb1 = (const float*)d_in[23];
    const float* mw2 = (const float*)d_in[24];
    const float* mb2 = (const float*)d_in[25];

    const size_t MB = 1u << 20;
    char* ws = (char*)d_ws;
    // lifetimes: z1 dead before Qb written; agg dead before Oml written;
    // Opart dead (after combine) before hidden written.
    __bf16* Hb      = (__bf16*)(ws);            // 2 MB  layer input h
    __bf16* h1b     = (__bf16*)(ws + 2*MB);     // 2 MB
    __bf16* h2b     = (__bf16*)(ws + 4*MB);     // 2 MB
    __bf16* zbuf    = (__bf16*)(ws + 6*MB);     // 2 MB  shared pre-BN
    __bf16* Qb      = (__bf16*)(ws + 8*MB);     // 2 MB  (z1 overlay)
    __bf16* z1b     = Qb;
    __bf16* Kb      = (__bf16*)(ws + 10*MB);    // 2 MB
    __bf16* Vb      = (__bf16*)(ws + 12*MB);    // 2 MB
    __bf16* Ob      = (__bf16*)(ws + 14*MB);    // 2 MB
    float*  agg     = (float*)(ws + 16*MB);     // 4 MB
    float2* Oml     = (float2*)(ws + 16*MB);    // 1 MB (agg overlay)
    __bf16* Opart   = (__bf16*)(ws + 20*MB);    // 8 MB
    __bf16* hiddenb = (__bf16*)(ws + 20*MB);    // 4 MB (Opart overlay)
    __bf16* Wb      = (__bf16*)(ws + 28*MB);    // ~3.93 MB
    float*  stats   = (float*)(ws + 32*MB);     // 9 x 2C

    dim3 blk(256);
    dim3 gemmCC(4, 64);
    dim3 gemmC2(8, 64);

    prep_w<<<dim3(384, 8), blk, 0, stream>>>(gin_w1, gin_w2, wq, wk, wv, wo, mw1, mw2, Wb);
    hipMemsetAsync(stats, 0, 9 * 2 * C * sizeof(float), stream);
    lin1_kernel<<<NN, blk, 0, stream>>>(x, lin1_w, lin1_b, Hb);

    for (int l = 0; l < NL; l++) {
        const int CC1 = C*C;
        const __bf16* gw1b = Wb + (size_t)l*CC1;
        const __bf16* gw2b = Wb + CCL + (size_t)l*CC1;
        const __bf16* wqp  = Wb + 2*CCL + (size_t)l*CC1;
        const __bf16* wkp  = Wb + 3*CCL + (size_t)l*CC1;
        const __bf16* wvp  = Wb + 4*CCL + (size_t)l*CC1;
        const __bf16* wop  = Wb + 5*CCL + (size_t)l*CC1;
        const __bf16* mw1p = Wb + 6*CCL + (size_t)l*2*CC1;
        const __bf16* mw2p = Wb + 8*CCL + (size_t)l*2*CC1;
        const float* gb1 = gin_b1 + (size_t)l*C;
        const float* gb2 = gin_b2 + (size_t)l*C;
        const float* lbq = bq + (size_t)l*C;
        const float* lbk = bk + (size_t)l*C;
        const float* lbv = bv + (size_t)l*C;
        const float* lbo = bo + (size_t)l*C;
        const float* lmb1 = mb1 + (size_t)l*2*C;
        const float* lmb2 = mb2 + (size_t)l*C;
        float* st1 = stats + (size_t)l*3*2*C;
        float* st2 = st1 + 2*C;
        float* st3 = st2 + 2*C;

        // ---- GIN branch ----
        hipMemsetAsync(agg, 0, (size_t)NN*C*sizeof(float), stream);
        scatter_kernel<<<NE/4, blk, 0, stream>>>(Hb, ei, agg);
        gemm_bf16<<<gemmCC, blk, 0, stream>>>(Hb, agg, nullptr, gw1b, gb1, nullptr, nullptr, z1b, nullptr, C, C, 1);
        gemm_bf16<<<gemmCC, blk, 0, stream>>>(z1b, nullptr, nullptr, gw2b, gb2, Hb, nullptr, zbuf, st1, C, C, 0);
        bn_apply_kernel<<<NN/4, blk, 0, stream>>>(zbuf, st1, bn1_g + (size_t)l*C, bn1_b + (size_t)l*C, h1b, nullptr);

        // ---- attention branch ----
        qkv_gemm<<<dim3(4, 64, 3), blk, 0, stream>>>(Hb, wqp, wkp, wvp, lbq, lbk, lbv, Qb, Kb, Vb);
        attn_kernel<<<dim3(NN/128, NH, SPLIT), blk, 0, stream>>>(Qb, Kb, Vb, Opart, Oml);
        attn_combine<<<NN, blk, 0, stream>>>(Opart, Oml, Ob);
        gemm_bf16<<<gemmCC, blk, 0, stream>>>(Ob, nullptr, nullptr, wop, lbo, Hb, nullptr, zbuf, st2, C, C, 0);
        bn_apply_kernel<<<NN/4, blk, 0, stream>>>(zbuf, st2, bn2_g + (size_t)l*C, bn2_b + (size_t)l*C, h2b, nullptr);

        // ---- feedforward ----
        gemm_bf16<<<gemmC2, blk, 0, stream>>>(h1b, nullptr, h2b, mw1p, lmb1, nullptr, nullptr, hiddenb, nullptr, C, 2*C, 1);
        gemm_bf16<<<gemmCC, blk, 0, stream>>>(hiddenb, nullptr, nullptr, mw2p, lmb2, h1b, h2b, zbuf, st3, 2*C, C, 0);
        if (l == NL-1)
            bn_apply_kernel<<<NN/4, blk, 0, stream>>>(zbuf, st3, bn3_g + (size_t)l*C, bn3_b + (size_t)l*C, nullptr, (float*)d_out);
        else
            bn_apply_kernel<<<NN/4, blk, 0, stream>>>(zbuf, st3, bn3_g + (size_t)l*C, bn3_b + (size_t)l*C, Hb, nullptr);
    }
}

// Round 7
// 581.881 us; speedup vs baseline: 2.0408x; 2.0408x over previous
//
#include <hip/hip_runtime.h>

#define NN 4096
#define NE 65536
#define C 256
#define NL 3
#define NH 8
#define DH 32
#define EPS 1e-5f
#define SPLIT 4          // key-dim split for attention occupancy
#define KT_PER (NN/64/SPLIT)

typedef __bf16 bf16x8 __attribute__((ext_vector_type(8)));
typedef __bf16 bf16x4v __attribute__((ext_vector_type(4)));
typedef float f32x4 __attribute__((ext_vector_type(4)));
typedef short bf16x4s __attribute__((ext_vector_type(4)));   // 4 bf16 as i16x4

// scale * log2(e), folded into Q at projection time so softmax uses exp2
#define QSCALE (0.17677669529663687f * 1.4426950408889634f)

#define CCL (NL*C*C)     // 196608: elems of one [L,C,C] weight group

// ---------------- weight prep: fp32 -> bf16, all 8 groups ----------------
__global__ __launch_bounds__(256) void prep_w(const float* __restrict__ s0,
        const float* __restrict__ s1, const float* __restrict__ s2,
        const float* __restrict__ s3, const float* __restrict__ s4,
        const float* __restrict__ s5, const float* __restrict__ s6,
        const float* __restrict__ s7, __bf16* __restrict__ dst) {
    int g = blockIdx.y;
    int i = (blockIdx.x*256 + threadIdx.x)*4;
    const float* src; size_t off; int n;
    switch (g) {
        case 0: src=s0; off=0;        n=CCL;   break;
        case 1: src=s1; off=CCL;      n=CCL;   break;
        case 2: src=s2; off=2*CCL;    n=CCL;   break;
        case 3: src=s3; off=3*CCL;    n=CCL;   break;
        case 4: src=s4; off=4*CCL;    n=CCL;   break;
        case 5: src=s5; off=5*CCL;    n=CCL;   break;
        case 6: src=s6; off=6*CCL;    n=2*CCL; break;
        default: src=s7; off=8*CCL;   n=2*CCL; break;
    }
    if (i < n) {
        float4 t = *(const float4*)(src + i);
        bf16x4v o = {(__bf16)t.x, (__bf16)t.y, (__bf16)t.z, (__bf16)t.w};
        *(bf16x4v*)(dst + off + i) = o;
    }
}

// ---------------- lin1: h[n,c] = x[n]*w[c] + b[c], bf16 out ----------------
__global__ __launch_bounds__(256) void lin1_kernel(const float* __restrict__ x,
        const float* __restrict__ w, const float* __restrict__ b,
        __bf16* __restrict__ out) {
    int n = blockIdx.x, c = threadIdx.x;
    out[(size_t)n*C + c] = (__bf16)(x[n]*w[c] + b[c]);
}

// ---------------- CSR build: histogram -> scan -> fill ----------------
__global__ __launch_bounds__(256) void hist_kernel(const int* __restrict__ ei,
        int* __restrict__ cnt) {
    int e = blockIdx.x*256 + threadIdx.x;
    atomicAdd(&cnt[ei[NE + e]], 1);
}

__global__ __launch_bounds__(256) void scan_kernel(const int* __restrict__ cnt,
        int* __restrict__ rowptr, int* __restrict__ cursor) {
    __shared__ int tot[256];
    __shared__ int pre[257];
    int t = threadIdx.x;
    int base = t*16;
    int local[16];
    int s = 0;
    #pragma unroll
    for (int i = 0; i < 16; i++) { local[i] = s; s += cnt[base+i]; }
    tot[t] = s;
    __syncthreads();
    if (t == 0) {
        int acc = 0;
        for (int i = 0; i < 256; i++) { pre[i] = acc; acc += tot[i]; }
        pre[256] = acc;
    }
    __syncthreads();
    int off = pre[t];
    #pragma unroll
    for (int i = 0; i < 16; i++) {
        rowptr[base+i] = off + local[i];
        cursor[base+i] = off + local[i];
    }
    if (t == 0) rowptr[NN] = pre[256];
}

__global__ __launch_bounds__(256) void fill_kernel(const int* __restrict__ ei,
        int* __restrict__ cursor, int* __restrict__ eidsrc) {
    int e = blockIdx.x*256 + threadIdx.x;
    int dst = ei[NE + e], src = ei[e];
    int pos = atomicAdd(&cursor[dst], 1);
    eidsrc[pos] = src;
}

// ---------------- gather aggregation: agg[dst] = sum h[src] ----------------
// one block per dst node, thread = channel; no float atomics, writes zeros
// for deg-0 nodes (so no memset needed).
__global__ __launch_bounds__(256) void agg_kernel(const __bf16* __restrict__ h,
        const int* __restrict__ rowptr, const int* __restrict__ eidsrc,
        float* __restrict__ agg) {
    int dst = blockIdx.x, t = threadIdx.x;
    int beg = rowptr[dst], end = rowptr[dst+1];
    float s = 0.f;
    for (int e = beg; e < end; e++) {
        int src = eidsrc[e];
        s += (float)h[(size_t)src*C + t];
    }
    agg[(size_t)dst*C + t] = s;
}

// ---------------- all-bf16 MFMA GEMM ----------------
// out = relu?((A [+A2f|+A2b]) @ W^T + bias) + add1 + add2; bf16 in/out, fp32
// accum. Optional BN partial stats. Tile 64x64, BK=64, 256 thr = 4 waves.
#define GS 72   // LDS row stride in bf16 (144B: rows offset 4 banks -> 2-way, free)
__global__ __launch_bounds__(256) void gemm_bf16(const __bf16* __restrict__ A,
        const float* __restrict__ A2f, const __bf16* __restrict__ A2b,
        const __bf16* __restrict__ W, const float* __restrict__ bias,
        const __bf16* __restrict__ add1, const __bf16* __restrict__ add2,
        __bf16* __restrict__ out, float* __restrict__ stats,
        int K, int Nout, int relu) {
    __shared__ __bf16 As[64*GS];
    __shared__ __bf16 Ws[64*GS];
    int tid = threadIdx.x;
    int wave = tid >> 6, lane = tid & 63;
    int ln = lane & 15, quad = lane >> 4;
    int bm = blockIdx.y * 64, bn = blockIdx.x * 64;
    int row = tid >> 2, kseg = (tid & 3) * 16;
    f32x4 acc[4] = {};
    for (int k0 = 0; k0 < K; k0 += 64) {
        __syncthreads();
        {
            const __bf16* ap = &A[(size_t)(bm+row)*K + k0 + kseg];
            bf16x8 a0 = *(const bf16x8*)ap;
            bf16x8 a1 = *(const bf16x8*)(ap + 8);
            if (A2f) {
                const float* p = &A2f[(size_t)(bm+row)*K + k0 + kseg];
                #pragma unroll
                for (int i = 0; i < 2; i++) {
                    float4 t0 = *(const float4*)(p + i*8);
                    float4 t1 = *(const float4*)(p + i*8 + 4);
                    bf16x8& a = i ? a1 : a0;
                    a[0] = (__bf16)((float)a[0] + t0.x); a[1] = (__bf16)((float)a[1] + t0.y);
                    a[2] = (__bf16)((float)a[2] + t0.z); a[3] = (__bf16)((float)a[3] + t0.w);
                    a[4] = (__bf16)((float)a[4] + t1.x); a[5] = (__bf16)((float)a[5] + t1.y);
                    a[6] = (__bf16)((float)a[6] + t1.z); a[7] = (__bf16)((float)a[7] + t1.w);
                }
            } else if (A2b) {
                const __bf16* p = &A2b[(size_t)(bm+row)*K + k0 + kseg];
                bf16x8 b0 = *(const bf16x8*)p;
                bf16x8 b1 = *(const bf16x8*)(p + 8);
                #pragma unroll
                for (int j = 0; j < 8; j++) {
                    a0[j] = (__bf16)((float)a0[j] + (float)b0[j]);
                    a1[j] = (__bf16)((float)a1[j] + (float)b1[j]);
                }
            }
            *(bf16x8*)&As[row*GS + kseg]     = a0;
            *(bf16x8*)&As[row*GS + kseg + 8] = a1;
            const __bf16* wp = &W[(size_t)(bn+row)*K + k0 + kseg];
            *(bf16x8*)&Ws[row*GS + kseg]     = *(const bf16x8*)wp;
            *(bf16x8*)&Ws[row*GS + kseg + 8] = *(const bf16x8*)(wp + 8);
        }
        __syncthreads();
        #pragma unroll
        for (int kt2 = 0; kt2 < 2; kt2++) {
            bf16x8 bfr = *(const bf16x8*)&Ws[(wave*16+ln)*GS + kt2*32 + quad*8];
            #pragma unroll
            for (int i = 0; i < 4; i++) {
                bf16x8 afr = *(const bf16x8*)&As[(i*16+ln)*GS + kt2*32 + quad*8];
                acc[i] = __builtin_amdgcn_mfma_f32_16x16x32_bf16(afr, bfr, acc[i], 0, 0, 0);
            }
        }
    }
    int col = bn + wave*16 + ln;
    float bsv = bias[col];
    float ssum = 0.f, ssq = 0.f;
    #pragma unroll
    for (int i = 0; i < 4; i++) {
        #pragma unroll
        for (int r = 0; r < 4; r++) {
            int rw = bm + i*16 + quad*4 + r;
            float vv = acc[i][r] + bsv;
            if (relu) vv = fmaxf(vv, 0.f);
            size_t idx = (size_t)rw*Nout + col;
            if (add1) vv += (float)add1[idx];
            if (add2) vv += (float)add2[idx];
            out[idx] = (__bf16)vv;
            ssum += vv; ssq += vv*vv;
        }
    }
    if (stats) {
        ssum += __shfl_xor(ssum, 16); ssum += __shfl_xor(ssum, 32);
        ssq  += __shfl_xor(ssq, 16);  ssq  += __shfl_xor(ssq, 32);
        if (quad == 0) {
            atomicAdd(&stats[col], ssum);
            atomicAdd(&stats[Nout + col], ssq);
        }
    }
}

// ---------------- fused QKV projection, all-bf16 ----------------
__global__ __launch_bounds__(256) void qkv_gemm(const __bf16* __restrict__ A,
        const __bf16* __restrict__ wq, const __bf16* __restrict__ wk,
        const __bf16* __restrict__ wv, const float* __restrict__ bq,
        const float* __restrict__ bk, const float* __restrict__ bv,
        __bf16* __restrict__ qo, __bf16* __restrict__ ko,
        __bf16* __restrict__ vo) {
    int z = blockIdx.z;
    const __bf16* W   = z == 0 ? wq : (z == 1 ? wk : wv);
    const float* bias = z == 0 ? bq : (z == 1 ? bk : bv);
    __bf16* out       = z == 0 ? qo : (z == 1 ? ko : vo);
    float oscale      = z == 0 ? QSCALE : 1.0f;
    __shared__ __bf16 As[64*GS];
    __shared__ __bf16 Ws[64*GS];
    int tid = threadIdx.x;
    int wave = tid >> 6, lane = tid & 63;
    int ln = lane & 15, quad = lane >> 4;
    int bm = blockIdx.y * 64, bn = blockIdx.x * 64;
    int row = tid >> 2, kseg = (tid & 3) * 16;
    f32x4 acc[4] = {};
    for (int k0 = 0; k0 < C; k0 += 64) {
        __syncthreads();
        {
            const __bf16* ap = &A[(size_t)(bm+row)*C + k0 + kseg];
            *(bf16x8*)&As[row*GS + kseg]     = *(const bf16x8*)ap;
            *(bf16x8*)&As[row*GS + kseg + 8] = *(const bf16x8*)(ap + 8);
            const __bf16* wp = &W[(size_t)(bn+row)*C + k0 + kseg];
            *(bf16x8*)&Ws[row*GS + kseg]     = *(const bf16x8*)wp;
            *(bf16x8*)&Ws[row*GS + kseg + 8] = *(const bf16x8*)(wp + 8);
        }
        __syncthreads();
        #pragma unroll
        for (int kt2 = 0; kt2 < 2; kt2++) {
            bf16x8 bfr = *(const bf16x8*)&Ws[(wave*16+ln)*GS + kt2*32 + quad*8];
            #pragma unroll
            for (int i = 0; i < 4; i++) {
                bf16x8 afr = *(const bf16x8*)&As[(i*16+ln)*GS + kt2*32 + quad*8];
                acc[i] = __builtin_amdgcn_mfma_f32_16x16x32_bf16(afr, bfr, acc[i], 0, 0, 0);
            }
        }
    }
    int col = bn + wave*16 + ln;
    float bsv = bias[col];
    #pragma unroll
    for (int i = 0; i < 4; i++)
        #pragma unroll
        for (int r = 0; r < 4; r++) {
            int rw = bm + i*16 + quad*4 + r;
            out[(size_t)rw*C + col] = (__bf16)((acc[i][r] + bsv) * oscale);
        }
}

// ---------------- BatchNorm apply: bf16 in, bf16 or fp32 out ----------------
__global__ __launch_bounds__(256) void bn_apply_kernel(const __bf16* __restrict__ z,
        const float* __restrict__ stats, const float* __restrict__ g,
        const float* __restrict__ b, __bf16* __restrict__ outb,
        float* __restrict__ outf) {
    int idx4 = (blockIdx.x*256 + threadIdx.x) * 4;
    int c = idx4 & (C-1);
    bf16x4v zv = *(const bf16x4v*)&z[idx4];
    float4 st = *(const float4*)&stats[c];
    float4 sq = *(const float4*)&stats[C + c];
    float4 gv = *(const float4*)&g[c];
    float4 bv = *(const float4*)&b[c];
    float o[4];
    float mean0 = st.x*(1.f/NN), mean1 = st.y*(1.f/NN), mean2 = st.z*(1.f/NN), mean3 = st.w*(1.f/NN);
    o[0] = ((float)zv[0] - mean0) * rsqrtf(sq.x*(1.f/NN) - mean0*mean0 + EPS) * gv.x + bv.x;
    o[1] = ((float)zv[1] - mean1) * rsqrtf(sq.y*(1.f/NN) - mean1*mean1 + EPS) * gv.y + bv.y;
    o[2] = ((float)zv[2] - mean2) * rsqrtf(sq.z*(1.f/NN) - mean2*mean2 + EPS) * gv.z + bv.z;
    o[3] = ((float)zv[3] - mean3) * rsqrtf(sq.w*(1.f/NN) - mean3*mean3 + EPS) * gv.w + bv.w;
    if (outb) {
        bf16x4v ov = {(__bf16)o[0], (__bf16)o[1], (__bf16)o[2], (__bf16)o[3]};
        *(bf16x4v*)&outb[idx4] = ov;
    } else {
        float4 ov = {o[0], o[1], o[2], o[3]};
        *(float4*)&outf[idx4] = ov;
    }
}

// ---------------- bf16 MFMA flash attention, S^T formulation ----------------
__global__ __launch_bounds__(256) void attn_kernel(const __bf16* __restrict__ q,
        const __bf16* __restrict__ k, const __bf16* __restrict__ v,
        __bf16* __restrict__ opart, float2* __restrict__ ml) {
    __shared__ __bf16 Ks[64*36];            // [key][dh], row-major, pad 36
    int tid = threadIdx.x;
    int wave = tid >> 6, lane = tid & 63;
    int ln = lane & 15, quad = lane >> 4;
    int head = blockIdx.y;
    int hb = head * DH;
    int qb = blockIdx.x * 128;
    int z = blockIdx.z;

    bf16x8 qf[2];
    #pragma unroll
    for (int g = 0; g < 2; g++)
        qf[g] = *(const bf16x8*)&q[(size_t)(qb + wave*32 + g*16 + ln)*C + hb + quad*8];

    f32x4 oacc[2][2] = {};
    float m_[2], l_[2];
    #pragma unroll
    for (int g = 0; g < 2; g++) { m_[g] = -1e30f; l_[g] = 0.f; }

    int srow = tid >> 2, sseg = (tid & 3) * 8;
    for (int kt = z*KT_PER; kt < (z+1)*KT_PER; kt++) {
        int kb = kt * 64;
        union { __bf16 b[4]; bf16x4s s; } vf[4][2];
        {
            const __bf16* vb = v + ((size_t)kb + quad*4)*C + hb + ln;
            #pragma unroll
            for (int sub = 0; sub < 4; sub++)
                #pragma unroll
                for (int h = 0; h < 2; h++)
                    #pragma unroll
                    for (int j = 0; j < 4; j++)
                        vf[sub][h].b[j] = vb[(size_t)(sub*16 + j)*C + h*16];
        }
        __syncthreads();
        *(bf16x8*)&Ks[srow*36 + sseg] = *(const bf16x8*)&k[(size_t)(kb+srow)*C + hb + sseg];
        __syncthreads();

        f32x4 st[2][4];
        #pragma unroll
        for (int sub = 0; sub < 4; sub++) {
            bf16x8 af = *(const bf16x8*)&Ks[(sub*16+ln)*36 + quad*8];
            #pragma unroll
            for (int g = 0; g < 2; g++) {
                f32x4 zz = {0.f,0.f,0.f,0.f};
                st[g][sub] = __builtin_amdgcn_mfma_f32_16x16x32_bf16(af, qf[g], zz, 0, 0, 0);
            }
        }
        #pragma unroll
        for (int g = 0; g < 2; g++) {
            float tm = st[g][0][0];
            #pragma unroll
            for (int sub = 0; sub < 4; sub++)
                #pragma unroll
                for (int r = 0; r < 4; r++)
                    tm = fmaxf(tm, st[g][sub][r]);
            tm = fmaxf(tm, __shfl_xor(tm, 16));
            tm = fmaxf(tm, __shfl_xor(tm, 32));
            float nm = fmaxf(m_[g], tm);
            float al = __builtin_amdgcn_exp2f(m_[g] - nm);
            m_[g] = nm;
            float ps = 0.f;
            union { __bf16 b[4]; bf16x4s s; } pf[4];
            #pragma unroll
            for (int sub = 0; sub < 4; sub++)
                #pragma unroll
                for (int r = 0; r < 4; r++) {
                    float p = __builtin_amdgcn_exp2f(st[g][sub][r] - nm);
                    pf[sub].b[r] = (__bf16)p;
                    ps += p;
                }
            ps += __shfl_xor(ps, 16);
            ps += __shfl_xor(ps, 32);
            l_[g] = l_[g]*al + ps;
            #pragma unroll
            for (int r = 0; r < 4; r++) {
                float ar = __shfl(al, (lane & 48) | (quad*4 + r));
                oacc[g][0][r] *= ar;
                oacc[g][1][r] *= ar;
            }
            #pragma unroll
            for (int sub = 0; sub < 4; sub++) {
                oacc[g][0] = __builtin_amdgcn_mfma_f32_16x16x16bf16_1k(
                        pf[sub].s, vf[sub][0].s, oacc[g][0], 0, 0, 0);
                oacc[g][1] = __builtin_amdgcn_mfma_f32_16x16x16bf16_1k(
                        pf[sub].s, vf[sub][1].s, oacc[g][1], 0, 0, 0);
            }
        }
    }
    #pragma unroll
    for (int g = 0; g < 2; g++) {
        #pragma unroll
        for (int r = 0; r < 4; r++) {
            float lr = __shfl(l_[g], (lane & 48) | (quad*4 + r));
            float inv = 1.0f / lr;
            int row = qb + wave*32 + g*16 + quad*4 + r;
            size_t base = ((size_t)z*NN + row)*C + hb;
            opart[base + ln]      = (__bf16)(oacc[g][0][r] * inv);
            opart[base + 16 + ln] = (__bf16)(oacc[g][1][r] * inv);
        }
        if (quad == 0) {
            int qrow = qb + wave*32 + g*16 + ln;
            ml[((size_t)z*NH + head)*NN + qrow] = make_float2(m_[g], l_[g]);
        }
    }
}

// ---------------- combine split-K attention partials, bf16 out ----------------
__global__ __launch_bounds__(256) void attn_combine(const __bf16* __restrict__ opart,
        const float2* __restrict__ ml, __bf16* __restrict__ o) {
    int row = blockIdx.x, c = threadIdx.x;
    int head = c >> 5;
    float2 t[SPLIT];
    float M = -1e30f;
    #pragma unroll
    for (int z = 0; z < SPLIT; z++) {
        t[z] = ml[((size_t)z*NH + head)*NN + row];
        M = fmaxf(M, t[z].x);
    }
    float acc = 0.f, wsum = 0.f;
    #pragma unroll
    for (int z = 0; z < SPLIT; z++) {
        float w = t[z].y * __builtin_amdgcn_exp2f(t[z].x - M);
        acc += w * (float)opart[((size_t)z*NN + row)*C + c];
        wsum += w;
    }
    o[(size_t)row*C + c] = (__bf16)(acc / wsum);
}

extern "C" void kernel_launch(void* const* d_in, const int* in_sizes, int n_in,
                              void* d_out, int out_size, void* d_ws, size_t ws_size,
                              hipStream_t stream) {
    const float* x      = (const float*)d_in[0];
    const int*   ei     = (const int*)d_in[1];
    const float* lin1_w = (const float*)d_in[2];
    const float* lin1_b = (const float*)d_in[3];
    const float* gin_w1 = (const float*)d_in[4];
    const float* gin_b1 = (const float*)d_in[5];
    const float* gin_w2 = (const float*)d_in[6];
    const float* gin_b2 = (const float*)d_in[7];
    const float* wq = (const float*)d_in[8];
    const float* wk = (const float*)d_in[9];
    const float* wv = (const float*)d_in[10];
    const float* wo = (const float*)d_in[11];
    const float* bq = (const float*)d_in[12];
    const float* bk = (const float*)d_in[13];
    const float* bv = (const float*)d_in[14];
    const float* bo = (const float*)d_in[15];
    const float* bn1_g = (const float*)d_in[16];
    const float* bn1_b = (const float*)d_in[17];
    const float* bn2_g = (const float*)d_in[18];
    const float* bn2_b = (const float*)d_in[19];
    const float* bn3_g = (const float*)d_in[20];
    const float* bn3_b = (const float*)d_in[21];
    const float* mw1 = (const float*)d_in[22];
    const float* mb1 = (const float*)d_in[23];
    const float* mw2 = (const float*)d_in[24];
    const float* mb2 = (const float*)d_in[25];

    const size_t MB = 1u << 20;
    char* ws = (char*)d_ws;
    // lifetimes: z1 dead before Qb written; agg dead before Oml written;
    // Opart dead (after combine) before hidden written.
    __bf16* Hb      = (__bf16*)(ws);            // 2 MB  layer input h
    __bf16* h1b     = (__bf16*)(ws + 2*MB);     // 2 MB
    __bf16* h2b     = (__bf16*)(ws + 4*MB);     // 2 MB
    __bf16* zbuf    = (__bf16*)(ws + 6*MB);     // 2 MB  shared pre-BN
    __bf16* Qb      = (__bf16*)(ws + 8*MB);     // 2 MB  (z1 overlay)
    __bf16* z1b     = Qb;
    __bf16* Kb      = (__bf16*)(ws + 10*MB);    // 2 MB
    __bf16* Vb      = (__bf16*)(ws + 12*MB);    // 2 MB
    __bf16* Ob      = (__bf16*)(ws + 14*MB);    // 2 MB
    float*  agg     = (float*)(ws + 16*MB);     // 4 MB
    float2* Oml     = (float2*)(ws + 16*MB);    // 1 MB (agg overlay)
    __bf16* Opart   = (__bf16*)(ws + 20*MB);    // 8 MB
    __bf16* hiddenb = (__bf16*)(ws + 20*MB);    // 4 MB (Opart overlay)
    __bf16* Wb      = (__bf16*)(ws + 28*MB);    // ~3.93 MB
    float*  stats   = (float*)(ws + 32*MB);     // 9 x 2C floats
    int*    cursor  = (int*)(ws + 33*MB);       // 4096 ints (cnt, then cursor)
    int*    rowptr  = (int*)(ws + 33*MB + 32*1024);   // 4097 ints
    int*    eidsrc  = (int*)(ws + 33*MB + 64*1024);   // 65536 ints

    dim3 blk(256);
    dim3 gemmCC(4, 64);
    dim3 gemmC2(8, 64);

    prep_w<<<dim3(384, 8), blk, 0, stream>>>(gin_w1, gin_w2, wq, wk, wv, wo, mw1, mw2, Wb);
    hipMemsetAsync(stats, 0, 9 * 2 * C * sizeof(float), stream);
    lin1_kernel<<<NN, blk, 0, stream>>>(x, lin1_w, lin1_b, Hb);

    // ---- CSR build (once; edge_index is layer-invariant) ----
    hipMemsetAsync(cursor, 0, NN * sizeof(int), stream);
    hist_kernel<<<NE/256, blk, 0, stream>>>(ei, cursor);      // cursor = counts
    scan_kernel<<<1, blk, 0, stream>>>(cursor, rowptr, cursor);
    fill_kernel<<<NE/256, blk, 0, stream>>>(ei, cursor, eidsrc);

    for (int l = 0; l < NL; l++) {
        const int CC1 = C*C;
        const __bf16* gw1b = Wb + (size_t)l*CC1;
        const __bf16* gw2b = Wb + CCL + (size_t)l*CC1;
        const __bf16* wqp  = Wb + 2*CCL + (size_t)l*CC1;
        const __bf16* wkp  = Wb + 3*CCL + (size_t)l*CC1;
        const __bf16* wvp  = Wb + 4*CCL + (size_t)l*CC1;
        const __bf16* wop  = Wb + 5*CCL + (size_t)l*CC1;
        const __bf16* mw1p = Wb + 6*CCL + (size_t)l*2*CC1;
        const __bf16* mw2p = Wb + 8*CCL + (size_t)l*2*CC1;
        const float* gb1 = gin_b1 + (size_t)l*C;
        const float* gb2 = gin_b2 + (size_t)l*C;
        const float* lbq = bq + (size_t)l*C;
        const float* lbk = bk + (size_t)l*C;
        const float* lbv = bv + (size_t)l*C;
        const float* lbo = bo + (size_t)l*C;
        const float* lmb1 = mb1 + (size_t)l*2*C;
        const float* lmb2 = mb2 + (size_t)l*C;
        float* st1 = stats + (size_t)l*3*2*C;
        float* st2 = st1 + 2*C;
        float* st3 = st2 + 2*C;

        // ---- GIN branch (gather aggregation, no atomics, no memset) ----
        agg_kernel<<<NN, blk, 0, stream>>>(Hb, rowptr, eidsrc, agg);
        gemm_bf16<<<gemmCC, blk, 0, stream>>>(Hb, agg, nullptr, gw1b, gb1, nullptr, nullptr, z1b, nullptr, C, C, 1);
        gemm_bf16<<<gemmCC, blk, 0, stream>>>(z1b, nullptr, nullptr, gw2b, gb2, Hb, nullptr, zbuf, st1, C, C, 0);
        bn_apply_kernel<<<NN/4, blk, 0, stream>>>(zbuf, st1, bn1_g + (size_t)l*C, bn1_b + (size_t)l*C, h1b, nullptr);

        // ---- attention branch ----
        qkv_gemm<<<dim3(4, 64, 3), blk, 0, stream>>>(Hb, wqp, wkp, wvp, lbq, lbk, lbv, Qb, Kb, Vb);
        attn_kernel<<<dim3(NN/128, NH, SPLIT), blk, 0, stream>>>(Qb, Kb, Vb, Opart, Oml);
        attn_combine<<<NN, blk, 0, stream>>>(Opart, Oml, Ob);
        gemm_bf16<<<gemmCC, blk, 0, stream>>>(Ob, nullptr, nullptr, wop, lbo, Hb, nullptr, zbuf, st2, C, C, 0);
        bn_apply_kernel<<<NN/4, blk, 0, stream>>>(zbuf, st2, bn2_g + (size_t)l*C, bn2_b + (size_t)l*C, h2b, nullptr);

        // ---- feedforward ----
        gemm_bf16<<<gemmC2, blk, 0, stream>>>(h1b, nullptr, h2b, mw1p, lmb1, nullptr, nullptr, hiddenb, nullptr, C, 2*C, 1);
        gemm_bf16<<<gemmCC, blk, 0, stream>>>(hiddenb, nullptr, nullptr, mw2p, lmb2, h1b, h2b, zbuf, st3, 2*C, C, 0);
        if (l == NL-1)
            bn_apply_kernel<<<NN/4, blk, 0, stream>>>(zbuf, st3, bn3_g + (size_t)l*C, bn3_b + (size_t)l*C, nullptr, (float*)d_out);
        else
            bn_apply_kernel<<<NN/4, blk, 0, stream>>>(zbuf, st3, bn3_g + (size_t)l*C, bn3_b + (size_t)l*C, Hb, nullptr);
    }
}